// Round 2
// baseline (171.011 us; speedup 1.0000x reference)
//
#include <hip/hip_runtime.h>
#include <hip/hip_bf16.h>

typedef __attribute__((ext_vector_type(8))) short short8;
typedef __attribute__((ext_vector_type(4))) float f32x4;

#define L2E 1.44269504088896340736f

__device__ __forceinline__ float ipow(float x, int e) {
    float r = 1.f;
    for (int i = 0; i < e; ++i) r *= x;
    return r;
}

// ---------------------------------------------------------------------------
// prep_w: build a bf16 FRAGMENT-ORDERED image of w in d_ws (64 KB).
// Element idx in [0, 32768): frag = idx>>9, l = (idx>>3)&63, j = idx&7
//   frag = (chg*2 + kk)*2 + ct   (chg in [0,16), kk in {0,1}, ct in {0,1})
//   n = chg*64 + kk*32 + 8*(l>>4) + j   (B-fragment k-index mapping)
//   c = ct*16 + (l&15)                  (B-fragment col mapping)
// Main kernel then loads each B fragment as ONE coalesced dwordx4 per lane.
// ---------------------------------------------------------------------------
__global__ void prep_w(const float* __restrict__ w, unsigned short* __restrict__ img)
{
    int idx = blockIdx.x * 256 + threadIdx.x;      // 128 blocks x 256 = 32768
    int frag = idx >> 9, l = (idx >> 3) & 63, j = idx & 7;
    int ct = frag & 1, kk = (frag >> 1) & 1, chg = frag >> 2;
    int n = chg * 64 + kk * 32 + 8 * (l >> 4) + j;
    int c = ct * 16 + (l & 15);
    __hip_bfloat16 h = __float2bfloat16(w[n * 32 + c]);
    img[idx] = *(unsigned short*)&h;
}

// ---------------------------------------------------------------------------
// Main: Q=32768, N=1024, C=32. 1024 blocks x 256 threads (4 waves).
// Block covers 32 q-rows. wave wv: row-group rg=wv>>1 (16 rows), n-half=wv&1.
// Lane l: owns row m=l&15; kq=l>>4 strides the k dimension (A-fragment order).
// Each lane computes its exp values DIRECTLY in MFMA A-fragment layout —
// no LDS transpose. B-fragments stream from the L2-resident w image.
// Cross-wave (n-half) combine of row-sums and accumulators via tiny LDS.
// ---------------------------------------------------------------------------
__global__ __launch_bounds__(256, 4)
void rbf_main(const float* __restrict__ q_pos,
              const float* __restrict__ data_pos,
              const float* __restrict__ cmat,
              const int* __restrict__ poly_power,
              const unsigned short* __restrict__ wimg,
              float* __restrict__ out_val,    // [Q,32]
              float* __restrict__ out_kd,     // [Q,1024]
              float* __restrict__ out_poly)   // [Q,4]
{
    const int t  = threadIdx.x;
    const int l  = t & 63;
    const int wv = t >> 6;
    const int rg   = wv >> 1;     // row group (0/1)
    const int half = wv & 1;      // n half (0/1)
    const int q0 = blockIdx.x * 32 + rg * 16;
    const int m  = l & 15;
    const int kq = l >> 4;

    __shared__ float s_sum[2][2][16];
    __shared__ float s_acc[2][64][8];      // 4 KB

    const float qx = q_pos[(q0 + m) * 3 + 0];
    const float qy = q_pos[(q0 + m) * 3 + 1];
    const float qz = q_pos[(q0 + m) * 3 + 2];

    // ---- out_poly: 128 threads/block cover the block's 32 rows x 4 ----
    if (t < 128) {
        int q = blockIdx.x * 32 + (t >> 2), p = t & 3;
        int e0 = poly_power[p * 3], e1 = poly_power[p * 3 + 1], e2 = poly_power[p * 3 + 2];
        float x = q_pos[q * 3], y = q_pos[q * 3 + 1], z = q_pos[q * 3 + 2];
        out_poly[q * 4 + p] = ipow(x, e0) * ipow(y, e1) * ipow(z, e2);
    }

    // ---- phase 1: partial row-sum of exp(-r^2) over this wave's n-half ----
    float s = 0.f;
    for (int ck = 0; ck < 16; ++ck) {             // ck = ch*2 + kk
        int nb = half * 512 + (ck >> 1) * 64 + (ck & 1) * 32 + 8 * kq;
        const float* dp = data_pos + 3 * nb;
        float f[24];
#pragma unroll
        for (int i = 0; i < 6; ++i) *(float4*)&f[i * 4] = *(const float4*)(dp + i * 4);
#pragma unroll
        for (int j = 0; j < 8; ++j) {
            float dx = qx - f[3 * j], dy = qy - f[3 * j + 1], dz = qz - f[3 * j + 2];
            float r2 = dx * dx + dy * dy + dz * dz;
            s += __builtin_amdgcn_exp2f(r2 * (-L2E));
        }
    }
    // reduce the 4 kq copies of row m within the wave
    s += __shfl_xor(s, 16);
    s += __shfl_xor(s, 32);
    if (l < 16) s_sum[rg][half][m] = s;
    __syncthreads();
    const float invm = 1.0f / (s_sum[rg][0][m] + s_sum[rg][1][m]);

    // ---- phase 2: recompute exp in fragment order, MFMA, write out_kd ----
    f32x4 acc0 = {0.f, 0.f, 0.f, 0.f};
    f32x4 acc1 = {0.f, 0.f, 0.f, 0.f};
    const size_t kdrow = (size_t)(q0 + m) * 1024;

    for (int ck = 0; ck < 16; ++ck) {
        int ch = ck >> 1, kk = ck & 1;
        int chg = half * 8 + ch;
        int fb = ((chg * 2 + kk) * 2) * 512;       // element offset of frag (ct=0)
        // B fragments: coalesced 1 KB/wave loads from L2-resident image
        short8 b0 = *(const short8*)(wimg + fb + l * 8);
        short8 b1 = *(const short8*)(wimg + fb + 512 + l * 8);

        int nb = half * 512 + ch * 64 + kk * 32 + 8 * kq;
        const float* dp = data_pos + 3 * nb;
        float f[24];
#pragma unroll
        for (int i = 0; i < 6; ++i) *(float4*)&f[i * 4] = *(const float4*)(dp + i * 4);

        float v[8];
#pragma unroll
        for (int j = 0; j < 8; ++j) {
            float dx = qx - f[3 * j], dy = qy - f[3 * j + 1], dz = qz - f[3 * j + 2];
            float r2 = dx * dx + dy * dy + dz * dz;
            v[j] = __builtin_amdgcn_exp2f(r2 * (-L2E)) * invm;
        }
        // pack A fragment (already in fragment layout: row m, k = 8*kq + j)
        short8 a;
#pragma unroll
        for (int j = 0; j < 8; ++j) {
            __hip_bfloat16 h = __float2bfloat16(v[j]);
            a[j] = *(short*)&h;
        }
        acc0 = __builtin_amdgcn_mfma_f32_16x16x32_bf16(a, b0, acc0, 0, 0, 0);
        acc1 = __builtin_amdgcn_mfma_f32_16x16x32_bf16(a, b1, acc1, 0, 0, 0);

        // out_kd: 8 consecutive floats per lane -> two dwordx4 stores
        float4 st0 = {v[0], v[1], v[2], v[3]};
        float4 st1 = {v[4], v[5], v[6], v[7]};
        *(float4*)(out_kd + kdrow + nb)     = st0;
        *(float4*)(out_kd + kdrow + nb + 4) = st1;
    }

    // ---- combine accumulators across n-half wave pairs ----
    if (half == 1) {
#pragma unroll
        for (int i = 0; i < 4; ++i) {
            s_acc[rg][l][i]     = acc0[i];
            s_acc[rg][l][i + 4] = acc1[i];
        }
    }
    __syncthreads();
    if (half == 0) {
#pragma unroll
        for (int i = 0; i < 4; ++i) {
            acc0[i] += s_acc[rg][l][i];
            acc1[i] += s_acc[rg][l][i + 4];
        }
        int pw[12];
#pragma unroll
        for (int i = 0; i < 12; ++i) pw[i] = poly_power[i];
        float cp0[4], cp1[4];
#pragma unroll
        for (int p = 0; p < 4; ++p) {
            cp0[p] = cmat[p * 32 + m];
            cp1[p] = cmat[p * 32 + 16 + m];
        }
#pragma unroll
        for (int r = 0; r < 4; ++r) {
            int row = kq * 4 + r;                  // D row = (l>>4)*4 + reg
            int q = q0 + row;
            float x = q_pos[q * 3], y = q_pos[q * 3 + 1], z = q_pos[q * 3 + 2];
            float cv0 = 0.f, cv1 = 0.f;
#pragma unroll
            for (int p = 0; p < 4; ++p) {
                float pv = ipow(x, pw[p * 3]) * ipow(y, pw[p * 3 + 1]) * ipow(z, pw[p * 3 + 2]);
                cv0 += cp0[p] * pv;
                cv1 += cp1[p] * pv;
            }
            out_val[q * 32 + m]      = acc0[r] + cv0;
            out_val[q * 32 + 16 + m] = acc1[r] + cv1;
        }
    }
}

extern "C" void kernel_launch(void* const* d_in, const int* in_sizes, int n_in,
                              void* d_out, int out_size, void* d_ws, size_t ws_size,
                              hipStream_t stream) {
    const float* q_pos      = (const float*)d_in[0];
    const float* data_pos   = (const float*)d_in[1];
    const float* w          = (const float*)d_in[2];
    const float* cmat       = (const float*)d_in[3];
    const int*   poly_power = (const int*)d_in[4];

    const int Q = in_sizes[0] / 3;               // 32768
    float* out      = (float*)d_out;
    float* out_val  = out;                       // [Q,32]
    float* out_kd   = out + (size_t)Q * 32;      // [Q,1024]
    float* out_poly = out_kd + (size_t)Q * 1024; // [Q,4]

    unsigned short* wimg = (unsigned short*)d_ws;    // 64 KB fragment image

    prep_w<<<128, 256, 0, stream>>>(w, wimg);
    rbf_main<<<Q / 32, 256, 0, stream>>>(q_pos, data_pos, cmat, poly_power, wimg,
                                         out_val, out_kd, out_poly);
}